// Round 6
// baseline (171.703 us; speedup 1.0000x reference)
//
#include <hip/hip_runtime.h>
#include <math.h>

// Problem constants: B=16, T=8192, N=32, depth=31, 5 ops. n = 131072 elements.
constexpr int N_STACK = 32;
constexpr int DEPTH   = 31;
constexpr int NOPS    = 5;
constexpr int BLOCK   = 256;
constexpr int ROW     = DEPTH * NOPS;   // 155 dwords per elem (620 B, 4B-aligned)

#define LOG_LIMF 10.0f

typedef float v4 __attribute__((ext_vector_type(4)));

// ---------------- manual VMEM stream (volatile asm; mutual order fixed) ------
// Load one dword at compile-time byte offset OFF from a VGPR-pair pointer.
template<int QBASE, int NDW>
__device__ __forceinline__ void issue_chunk(const float* p, float* dst) {
#pragma unroll
    for (int j = 0; j < NDW; ++j)
        asm volatile("global_load_dword %0, %1, off offset:%c2"
                     : "=v"(dst[j]) : "v"(p), "i"(4 * (QBASE + j)));
}

__device__ __forceinline__ void issue_x4(const float* p, v4* dst, int i_times16) {
    // caller passes compile-time i*16 via template-free path below
}

// s_waitcnt with the chunk values as in/outs: consumers of a[] are forced
// below the wait; the wait cannot move relative to other volatile asm.
#define WAITC(NSTR, a) asm volatile("s_waitcnt vmcnt(" NSTR ")" : \
  "+v"((a)[0]),"+v"((a)[1]),"+v"((a)[2]),"+v"((a)[3]),"+v"((a)[4]),"+v"((a)[5]),\
  "+v"((a)[6]),"+v"((a)[7]),"+v"((a)[8]),"+v"((a)[9]),"+v"((a)[10]),"+v"((a)[11]),\
  "+v"((a)[12]),"+v"((a)[13]),"+v"((a)[14]),"+v"((a)[15]),"+v"((a)[16]),"+v"((a)[17]),\
  "+v"((a)[18]),"+v"((a)[19]),"+v"((a)[20]),"+v"((a)[21]),"+v"((a)[22]),"+v"((a)[23]),\
  "+v"((a)[24]),"+v"((a)[25]),"+v"((a)[26]),"+v"((a)[27]),"+v"((a)[28]),"+v"((a)[29]))

#define WAITC5(NSTR, a) asm volatile("s_waitcnt vmcnt(" NSTR ")" : \
  "+v"((a)[0]),"+v"((a)[1]),"+v"((a)[2]),"+v"((a)[3]),"+v"((a)[4]))

#define WAITSTK(NSTR, Sv, Lv) asm volatile("s_waitcnt vmcnt(" NSTR ")" : \
  "+v"((Sv)[0]),"+v"((Sv)[1]),"+v"((Sv)[2]),"+v"((Sv)[3]),\
  "+v"((Sv)[4]),"+v"((Sv)[5]),"+v"((Sv)[6]),"+v"((Sv)[7]),\
  "+v"((Lv)[0]),"+v"((Lv)[1]),"+v"((Lv)[2]),"+v"((Lv)[3]),\
  "+v"((Lv)[4]),"+v"((Lv)[5]),"+v"((Lv)[6]),"+v"((Lv)[7]))

// ---------------- verified numerics (absmax 0.0078 across rounds 1-5) --------
__device__ __forceinline__ float clip_log(float l) {
    float tx = 0.2f * l;
    tx = fminf(fmaxf(tx, -80.0f), 80.0f);
    float t = __expf(tx);
    return 10.0f * (t - 1.0f) * __builtin_amdgcn_rcpf(t + 1.0f);
}

__device__ __forceinline__ void add_ls(float sx, float lx, float sy, float ly,
                                       float l_same_c, float nlog, bool zres, bool bx,
                                       float &s_o, float &l_o)
{
    bool zx = (sx == 0.0f);
    bool zy = (sy == 0.0f);
    bool both = (!zx) && (!zy);
    bool same_sign = (sx * sy > 0.0f);
    bool same_br = both && same_sign;
    bool opp_br  = both && !same_sign;

    float s = 0.0f, l = 0.0f;
    if ((!zx) && zy) { s = sx; l = lx; }
    if (zx && (!zy)) { s = sy; l = ly; }
    if (same_br) { s = (sx > 0.0f) ? 1.0f : -1.0f; l = l_same_c; }
    if (opp_br)  { s = zres ? 0.0f : (bx ? sx : sy); l = nlog; }
    s_o = s;
    l_o = clip_log(l);
}

__device__ __forceinline__ void step_fn(float ss, float sl,
    float p0, float p1, float p2, float p3, float p4,
    float inv_cs, float &as_, float &al, float &S)
{
    float d = sl - al;
    float mx = fmaxf(sl, al);
    float lse = mx + __logf(1.0f + __expf(-fabsf(d)));   // logaddexp
    float l_same_c = clip_log(lse);

    bool bx = (sl >= al);
    float big    = bx ? sl : al;
    float small_ = bx ? al : sl;
    float delta = fminf(fmaxf(small_ - big, -LOG_LIMF), -0.001f);
    float diff = __logf(1.0f - __expf(delta));           // log1p(-exp(delta))
    bool zres = (small_ == big);
    float nlog = zres ? 0.0f : (big + diff);

    float s_add, l_add, s_sub, l_sub;
    add_ls(ss, sl,  as_, al, l_same_c, nlog, zres, bx, s_add, l_add);
    add_ls(ss, sl, -as_, al, l_same_c, nlog, zres, bx, s_sub, l_sub);

    float sm   = ss * as_;
    float lmul = clip_log(sl + al);
    float ldiv = clip_log(sl - al);

    float rs = p0 * s_add + p1 * s_sub + (p2 + p3) * sm + p4 * ss;
    float rl = p0 * l_add + p1 * l_sub + p2 * lmul + p3 * ldiv + p4 * sl;

    float ms = fmaf(rl, rl, S) * inv_cs + 1e-6f;
    float scale = fminf(10.0f * __builtin_amdgcn_rsqf(ms), 1.0f);
    rl *= scale;

    S = fmaf(-sl, sl, S);   // retire sec's original log from suffix sum
    as_ = rs;
    al  = rl;
}

// NS steps; probs from chunk buffer ch at dword base 5*JB; stack idx 30-k.
template<int KBASE, int JB, int NS>
__device__ __forceinline__ void run_steps(const float* ch,
    const float* s_arr, const float* l_arr, float &as_, float &al, float &S)
{
#pragma unroll
    for (int j = 0; j < NS; ++j) {
        const int k = KBASE + j;
        step_fn(s_arr[30 - k], l_arr[30 - k],
                ch[5*(JB+j)+0], ch[5*(JB+j)+1], ch[5*(JB+j)+2],
                ch[5*(JB+j)+3], ch[5*(JB+j)+4],
                1.0f / (float)(N_STACK - k), as_, al, S);
    }
}

// 512 blocks x 4 waves = 2048 waves = 2/SIMD cap; tell the register allocator.
__global__ __launch_bounds__(BLOCK)
__attribute__((amdgpu_waves_per_eu(2, 2)))
void stack_fold_kernel(const float* __restrict__ sgn,
                       const float* __restrict__ logm,
                       const float* __restrict__ ops,
                       float* __restrict__ out, int n)
{
    const unsigned id = blockIdx.x * BLOCK + threadIdx.x;   // grid exact: no guard

    const float* srow = sgn  + (size_t)id * N_STACK;  // 128 B, 16B-aligned
    const float* lrow = logm + (size_t)id * N_STACK;
    const float* orow = ops  + (size_t)id * ROW;      // 620 B, 4B-aligned

    // ---- prologue: issue stack (16 x dwordx4) + chunk0 (30 dw). out = 46 ----
    v4 Sv[8], Lv[8];
#pragma unroll
    for (int i = 0; i < 8; ++i)
        asm volatile("global_load_dwordx4 %0, %1, off offset:%c2"
                     : "=v"(Sv[i]) : "v"(srow), "i"(16 * i));
#pragma unroll
    for (int i = 0; i < 8; ++i)
        asm volatile("global_load_dwordx4 %0, %1, off offset:%c2"
                     : "=v"(Lv[i]) : "v"(lrow), "i"(16 * i));

    float A[30], B[30], C[30];
    issue_chunk<0, 30>(orow, A);          // steps 0-5

    WAITSTK("30", Sv, Lv);                // drain 16 oldest: stack ready; A in flight

    float s_arr[N_STACK], l_arr[N_STACK];
#pragma unroll
    for (int i = 0; i < 8; ++i) {
#pragma unroll
        for (int c = 0; c < 4; ++c) { s_arr[4*i+c] = Sv[i][c]; l_arr[4*i+c] = Lv[i][c]; }
    }

    float S = 0.0f;
#pragma unroll
    for (int i = 0; i < N_STACK - 1; ++i) S = fmaf(l_arr[i], l_arr[i], S);
    float as_ = s_arr[N_STACK - 1];
    float al  = l_arr[N_STACK - 1];

    issue_chunk<30, 30>(orow, B);         // steps 6-11.  outstanding <= 60 <= 63

    // ---- pipelined stages: consume k, issue k+2 mid-stage, wait never to 0 ----
    WAITC("30", A);                                        // A done; B in flight
    run_steps<0, 0, 2>(A, s_arr, l_arr, as_, al, S);
    issue_chunk<60, 30>(orow, C);                          // steps 12-17
    run_steps<2, 2, 4>(A, s_arr, l_arr, as_, al, S);

    WAITC("30", B);                                        // B done; C in flight
    run_steps<6, 0, 2>(B, s_arr, l_arr, as_, al, S);
    issue_chunk<90, 30>(orow, A);                          // steps 18-23 (A reused)
    run_steps<8, 2, 4>(B, s_arr, l_arr, as_, al, S);

    WAITC("30", C);
    run_steps<12, 0, 2>(C, s_arr, l_arr, as_, al, S);
    issue_chunk<120, 30>(orow, B);                         // steps 24-29 (B reused)
    run_steps<14, 2, 4>(C, s_arr, l_arr, as_, al, S);

    WAITC("30", A);
    run_steps<18, 0, 2>(A, s_arr, l_arr, as_, al, S);
    issue_chunk<150, 5>(orow, C);                          // step 30 (C reused, 5 dw)
    run_steps<20, 2, 4>(A, s_arr, l_arr, as_, al, S);

    WAITC("5", B);                                         // drain B; C5 in flight
    run_steps<24, 0, 6>(B, s_arr, l_arr, as_, al, S);

    WAITC5("0", C);                                        // last 5 dwords
    run_steps<30, 0, 1>(C, s_arr, l_arr, as_, al, S);

    // Output: (2, B, T) flat — [0..n) sign, [n..2n) log. Coalesced stores.
    out[id]     = as_;
    out[n + id] = al;
}

extern "C" void kernel_launch(void* const* d_in, const int* in_sizes, int n_in,
                              void* d_out, int out_size, void* d_ws, size_t ws_size,
                              hipStream_t stream) {
    const float* sgn  = (const float*)d_in[0];
    const float* logm = (const float*)d_in[1];
    const float* ops  = (const float*)d_in[2];
    float* out = (float*)d_out;

    int n = in_sizes[0] / N_STACK;        // B*T = 131072
    int blocks = n / BLOCK;               // 512 x 256
    stack_fold_kernel<<<blocks, BLOCK, 0, stream>>>(sgn, logm, ops, out, n);
}

// Round 7
// 157.183 us; speedup vs baseline: 1.0924x; 1.0924x over previous
//
#include <hip/hip_runtime.h>
#include <math.h>

// Problem constants: B=16, T=8192, N=32, depth=31, 5 ops. n = 131072 elements.
constexpr int N_STACK = 32;
constexpr int DEPTH   = 31;
constexpr int BLOCK   = 256;
constexpr int ROW     = 155;            // dwords per ops row (620 B, 4B-aligned)

#define LOG_LIMF 10.0f

// 16-B vector with 4-B alignment (ops rows are misaligned mod 16).
typedef float f4 __attribute__((ext_vector_type(4), aligned(4)));
__device__ __forceinline__ f4 ld4(const float* p) { return *reinterpret_cast<const f4*>(p); }

// ---------------- verified numerics (absmax 0.0078 across rounds 1-6) --------
__device__ __forceinline__ float clip_log(float l) {
    float tx = 0.2f * l;
    tx = fminf(fmaxf(tx, -80.0f), 80.0f);
    float t = __expf(tx);
    return 10.0f * (t - 1.0f) * __builtin_amdgcn_rcpf(t + 1.0f);
}

__device__ __forceinline__ void add_ls(float sx, float lx, float sy, float ly,
                                       float l_same_c, float nlog, bool zres, bool bx,
                                       float &s_o, float &l_o)
{
    bool zx = (sx == 0.0f);
    bool zy = (sy == 0.0f);
    bool both = (!zx) && (!zy);
    bool same_sign = (sx * sy > 0.0f);
    bool same_br = both && same_sign;
    bool opp_br  = both && !same_sign;

    float s = 0.0f, l = 0.0f;
    if ((!zx) && zy) { s = sx; l = lx; }
    if (zx && (!zy)) { s = sy; l = ly; }
    if (same_br) { s = (sx > 0.0f) ? 1.0f : -1.0f; l = l_same_c; }
    if (opp_br)  { s = zres ? 0.0f : (bx ? sx : sy); l = nlog; }
    s_o = s;
    l_o = clip_log(l);
}

__device__ __forceinline__ void step_fn(float ss, float sl,
    float p0, float p1, float p2, float p3, float p4,
    float inv_cs, float &as_, float &al, float &S)
{
    float d = sl - al;
    float mx = fmaxf(sl, al);
    float lse = mx + __logf(1.0f + __expf(-fabsf(d)));   // logaddexp
    float l_same_c = clip_log(lse);

    bool bx = (sl >= al);
    float big    = bx ? sl : al;
    float small_ = bx ? al : sl;
    float delta = fminf(fmaxf(small_ - big, -LOG_LIMF), -0.001f);
    float diff = __logf(1.0f - __expf(delta));           // log1p(-exp(delta))
    bool zres = (small_ == big);
    float nlog = zres ? 0.0f : (big + diff);

    float s_add, l_add, s_sub, l_sub;
    add_ls(ss, sl,  as_, al, l_same_c, nlog, zres, bx, s_add, l_add);
    add_ls(ss, sl, -as_, al, l_same_c, nlog, zres, bx, s_sub, l_sub);

    float sm   = ss * as_;
    float lmul = clip_log(sl + al);
    float ldiv = clip_log(sl - al);

    float rs = p0 * s_add + p1 * s_sub + (p2 + p3) * sm + p4 * ss;
    float rl = p0 * l_add + p1 * l_sub + p2 * lmul + p3 * ldiv + p4 * sl;

    float ms = fmaf(rl, rl, S) * inv_cs + 1e-6f;
    float scale = fminf(10.0f * __builtin_amdgcn_rsqf(ms), 1.0f);
    rl *= scale;

    S = fmaf(-sl, sl, S);   // retire sec's original log from suffix sum
    as_ = rs;
    al  = rl;
}

// __launch_bounds__(256, 2): min 2 waves/EU — the documented way to give the
// register allocator a ~256-VGPR budget (grid is hard-capped at 2 waves/SIMD).
// Outer loop ROLLED (4 iters x 8 unrolled steps): ~9 KB hot body fits the
// 32 KB I$, unlike the ~30 KB straight-line bodies of rounds 1-6.
__global__ __launch_bounds__(BLOCK, 2)
void stack_fold_kernel(const float* __restrict__ sgn,
                       const float* __restrict__ logm,
                       const float* __restrict__ ops,
                       float* __restrict__ out, int n)
{
    const unsigned id = blockIdx.x * BLOCK + threadIdx.x;   // grid exact

    const float* srow = sgn  + (size_t)id * N_STACK;  // 128 B, 16B-aligned
    const float* lrow = logm + (size_t)id * N_STACK;
    const float* orow = ops  + (size_t)id * ROW;      // 620 B, 4B-aligned

    // ---- prologue: stack (16 x dwordx4) + ops chunk 0 (10 x dwordx4) ----
    f4 sv[8], lv[8];
#pragma unroll
    for (int i = 0; i < 8; ++i) sv[i] = ld4(srow + 4 * i);
#pragma unroll
    for (int i = 0; i < 8; ++i) lv[i] = ld4(lrow + 4 * i);

    f4 cur[10], nxt[10];
#pragma unroll
    for (int i = 0; i < 10; ++i) cur[i] = ld4(orow + 4 * i);   // dw 0..39

    // Unpack stack. Window ws/wl holds orig[0..30]; acc = orig[31].
    float ws[DEPTH], wl[DEPTH];
    float S = 0.0f;
#pragma unroll
    for (int i = 0; i < 8; ++i) {
#pragma unroll
        for (int c = 0; c < 4; ++c) {
            int q = 4 * i + c;
            if (q < DEPTH) { ws[q] = sv[i][c]; wl[q] = lv[i][c]; S = fmaf(lv[i][c], lv[i][c], S); }
        }
    }
    float as_ = sv[7][3];
    float al  = lv[7][3];

    float fcs = 32.0f;          // running (32 - k); inv_cs via rcp (~1 ulp)

    // ---- rolled outer loop: chunk c holds steps 8c..8c+7 (last chunk: 7) ----
#pragma unroll 1
    for (int c = 0; c < 4; ++c) {
        // Issue next chunk's loads first (consumed next iteration).
        if (c < 3) {
            const float* nb = orow + 40 * (c + 1);
            if (c == 2) {
                // last chunk = dw 120..154 (35 dw): 8 x4 (120..151) + x4 at 151
#pragma unroll
                for (int i = 0; i < 8; ++i) nxt[i] = ld4(nb + 4 * i);
                nxt[8] = ld4(nb + 31);                 // dw 151..154
                nxt[9] = nxt[8];
            } else {
#pragma unroll
                for (int i = 0; i < 10; ++i) nxt[i] = ld4(nb + 4 * i);
            }
        }

        // Unpack current chunk into flat probs G[40] (waits on cur only).
        float G[40];
        if (c == 3) {
#pragma unroll
            for (int q = 0; q < 32; ++q) G[q] = cur[q >> 2][q & 3];  // dw 120+q
            G[32] = cur[8][1]; G[33] = cur[8][2]; G[34] = cur[8][3]; // dw 152..154
#pragma unroll
            for (int q = 35; q < 40; ++q) G[q] = 0.0f;               // unused
        } else {
#pragma unroll
            for (int q = 0; q < 40; ++q) G[q] = cur[q >> 2][q & 3];
        }

        // 8 unrolled steps (7 on the last chunk; uniform guard).
        const int nsteps = (c == 3) ? 7 : 8;
#pragma unroll
        for (int j = 0; j < 8; ++j) {
            if (j < nsteps) {
                float inv_cs = __builtin_amdgcn_rcpf(fcs);
                step_fn(ws[30 - j], wl[30 - j],
                        G[5*j+0], G[5*j+1], G[5*j+2], G[5*j+3], G[5*j+4],
                        inv_cs, as_, al, S);
                fcs -= 1.0f;
            }
        }

        // Shift window up by 8 so next iter's sec is again ws[30-j]; roll bufs.
        if (c < 3) {
#pragma unroll
            for (int m = 30; m >= 8; --m) { ws[m] = ws[m - 8]; wl[m] = wl[m - 8]; }
#pragma unroll
            for (int i = 0; i < 10; ++i) cur[i] = nxt[i];
        }
    }

    // Output: (2, B, T) flat — [0..n) sign, [n..2n) log. Coalesced stores.
    out[id]     = as_;
    out[n + id] = al;
}

extern "C" void kernel_launch(void* const* d_in, const int* in_sizes, int n_in,
                              void* d_out, int out_size, void* d_ws, size_t ws_size,
                              hipStream_t stream) {
    const float* sgn  = (const float*)d_in[0];
    const float* logm = (const float*)d_in[1];
    const float* ops  = (const float*)d_in[2];
    float* out = (float*)d_out;

    int n = in_sizes[0] / N_STACK;        // B*T = 131072
    int blocks = n / BLOCK;               // 512 x 256
    stack_fold_kernel<<<blocks, BLOCK, 0, stream>>>(sgn, logm, ops, out, n);
}